// Round 9
// baseline (394.275 us; speedup 1.0000x reference)
//
#include <hip/hip_runtime.h>
#include <cstdint>
#include <cstddef>

// ---------------------------------------------------------------------------
// QuantumNeuralNetwork fused pipeline for MI355X (gfx950)  — R9
//   K1: K-across-lanes, R=4 rows, acc[4][12] in regs. R8 spilled (WRITE_SIZE
//       50MB of scratch, xv[4][4]=64 VGPRs too many). Now ks-outer with
//       2-deep named ping-pong (xA/xB, 32 regs) -> ~95 VGPRs, no spill.
//       ds_reads unchanged: 12/row (16x less LDS than R2's 192/row).
//   K2: unchanged (R2 lane-per-(row,qubit) design, passing).
// Noise = JAX partitionable threefry: bits(i) = o0^o1 of
// threefry2x32(key=(0,1234), count=(0,i)), then XLA uniform->erfinv normal.
// ---------------------------------------------------------------------------

__device__ __forceinline__ uint32_t rotl32(uint32_t x, int r) {
  return (x << r) | (x >> (32 - r));
}

__device__ __forceinline__ void threefry2x32(uint32_t k0, uint32_t k1,
                                             uint32_t& x0, uint32_t& x1) {
  const uint32_t k2 = k0 ^ k1 ^ 0x1BD11BDAu;
  x0 += k0; x1 += k1;
#define TF_R(r) { x0 += x1; x1 = rotl32(x1, (r)); x1 ^= x0; }
  TF_R(13) TF_R(15) TF_R(26) TF_R(6)
  x0 += k1; x1 += k2 + 1u;
  TF_R(17) TF_R(29) TF_R(16) TF_R(24)
  x0 += k2; x1 += k0 + 2u;
  TF_R(13) TF_R(15) TF_R(26) TF_R(6)
  x0 += k0; x1 += k1 + 3u;
  TF_R(17) TF_R(29) TF_R(16) TF_R(24)
  x0 += k1; x1 += k2 + 4u;
  TF_R(13) TF_R(15) TF_R(26) TF_R(6)
  x0 += k2; x1 += k0 + 5u;
#undef TF_R
}

__device__ __forceinline__ float erfinv_xla(float x) {
  float w = -log1pf(-x * x);
  float p;
  if (w < 5.0f) {
    w -= 2.5f;
    p = 2.81022636e-08f;
    p = fmaf(p, w, 3.43273939e-07f);
    p = fmaf(p, w, -3.5233877e-06f);
    p = fmaf(p, w, -4.39150654e-06f);
    p = fmaf(p, w, 0.00021858087f);
    p = fmaf(p, w, -0.00125372503f);
    p = fmaf(p, w, -0.00417768164f);
    p = fmaf(p, w, 0.246640727f);
    p = fmaf(p, w, 1.50140941f);
  } else {
    w = sqrtf(w) - 3.0f;
    p = -0.000200214257f;
    p = fmaf(p, w, 0.000100950558f);
    p = fmaf(p, w, 0.00134934322f);
    p = fmaf(p, w, -0.00367342844f);
    p = fmaf(p, w, 0.00573950773f);
    p = fmaf(p, w, -0.0076224613f);
    p = fmaf(p, w, 0.00943887047f);
    p = fmaf(p, w, 1.00167406f);
    p = fmaf(p, w, 2.83297682f);
  }
  return p * x;
}

// ---------------------------------------------------------------------------
// K1: h[32768][12] = x @ w_in.T + b_in.
// grid 1024 x block 256 (4 waves). Wave covers 8 rows (2 R-blocks of 4).
// Lane l owns k = ks*256 + l*4 .. +3 for ks=0..3. Per R-block:
//   ks-outer, ping-pong xA/xB (2x4 float4 = 32 regs), acc[4][12] (48 regs).
//   48 unique ds_read_b128 of w, 768 FMA, 6-stage shfl_xor butterfly,
//   lanes 0..11 write 48B row coalesced.
// ---------------------------------------------------------------------------
__global__ __launch_bounds__(256, 3)
void qnn_gemm_in(const float* __restrict__ x, const float* __restrict__ w_in,
                 const float* __restrict__ b_in, float* __restrict__ h) {
  __shared__ float wl[12 * 1024];
  {
    const float4* ws = (const float4*)w_in;
    float4* wd = (float4*)wl;
#pragma unroll
    for (int j = 0; j < 12; ++j) wd[threadIdx.x + 256 * j] = ws[threadIdx.x + 256 * j];
  }
  __syncthreads();

  const int wave = threadIdx.x >> 6;
  const int lane = threadIdx.x & 63;
  const float bmy = (lane < 12) ? b_in[lane] : 0.0f;

#define K1_COMPUTE(KS, XV)                                                    \
  {                                                                           \
    _Pragma("unroll")                                                         \
    for (int q = 0; q < 12; ++q) {                                            \
      const float4 wv = *(const float4*)&wl[q * 1024 + ((KS) << 8) + (lane << 2)]; \
      _Pragma("unroll")                                                       \
      for (int r = 0; r < 4; ++r) {                                           \
        acc[r][q] = fmaf(XV[r].x, wv.x,                                       \
                    fmaf(XV[r].y, wv.y,                                       \
                    fmaf(XV[r].z, wv.z,                                       \
                    fmaf(XV[r].w, wv.w, acc[r][q]))));                        \
      }                                                                       \
    }                                                                         \
  }

#pragma unroll
  for (int blk = 0; blk < 2; ++blk) {
    const int row0 = (blockIdx.x << 5) + (wave << 3) + (blk << 2);
    const float* xb = x + (size_t)row0 * 1024;

    float acc[4][12];
#pragma unroll
    for (int r = 0; r < 4; ++r)
#pragma unroll
      for (int q = 0; q < 12; ++q) acc[r][q] = 0.0f;

    float4 xA[4], xB[4];
#pragma unroll
    for (int r = 0; r < 4; ++r) xA[r] = ((const float4*)(xb + r * 1024))[lane];        // ks0
#pragma unroll
    for (int r = 0; r < 4; ++r) xB[r] = ((const float4*)(xb + r * 1024))[64 + lane];   // ks1

    K1_COMPUTE(0, xA)
#pragma unroll
    for (int r = 0; r < 4; ++r) xA[r] = ((const float4*)(xb + r * 1024))[128 + lane];  // ks2
    K1_COMPUTE(1, xB)
#pragma unroll
    for (int r = 0; r < 4; ++r) xB[r] = ((const float4*)(xb + r * 1024))[192 + lane];  // ks3
    K1_COMPUTE(2, xA)
    K1_COMPUTE(3, xB)

#pragma unroll
    for (int r = 0; r < 4; ++r) {
      float hv[12];
#pragma unroll
      for (int q = 0; q < 12; ++q) {
        float v = acc[r][q];
        v += __shfl_xor(v, 1);
        v += __shfl_xor(v, 2);
        v += __shfl_xor(v, 4);
        v += __shfl_xor(v, 8);
        v += __shfl_xor(v, 16);
        v += __shfl_xor(v, 32);
        hv[q] = v;
      }
      float outv = hv[0];
#pragma unroll
      for (int q = 1; q < 12; ++q) outv = (lane == q) ? hv[q] : outv;
      if (lane < 12) h[(size_t)(row0 + r) * 12 + lane] = outv + bmy;
    }
  }
#undef K1_COMPUTE
}

// ---------------------------------------------------------------------------
// K2: grid 1024 x block 256, 32 rows/block (4 blocks/CU).
// Circuit: lane-per-(row,qubit): 16-lane groups, q = lane&15 (q<12 active),
// 4 rows/wave/pass, 2 passes. Entangle via __shfl(lane+/-1), LN via shfl_xor,
// mlp1 via 12 shfl broadcasts. Out-GEMM: thread t -> cols t, t+256.
// ---------------------------------------------------------------------------
__global__ __launch_bounds__(256, 4)
void qnn_tail(const float* __restrict__ h_in,
              const float* __restrict__ ln_g, const float* __restrict__ ln_b,
              const float* __restrict__ rot,  const float* __restrict__ ent,
              const float* __restrict__ w1,   const float* __restrict__ b1,
              const float* __restrict__ w2,   const float* __restrict__ b2,
              const float* __restrict__ meas, float* __restrict__ out) {
  __shared__ float w2s[512 * 12];
  __shared__ float b2s[512];
  __shared__ float hid[32 * 12];
  __shared__ float rot0s[8 * 16], sr1s[8 * 16], cr2s[8 * 16], cens[8 * 16];
  __shared__ float tmbs[16], w1T[12 * 16], b1s[16], lgs[16], lbs[16];

  const int t = threadIdx.x;

  {  // staging
    const float4* s = (const float4*)w2;
    float4* d = (float4*)w2s;
#pragma unroll
    for (int j = 0; j < 6; ++j) d[t + 256 * j] = s[t + 256 * j];
    if (t < 128) ((float4*)b2s)[t] = ((const float4*)b2)[t];
    if (t < 96) {
      const int l = t / 12, q = t % 12, base = (l * 12 + q) * 3;
      rot0s[l * 16 + q] = rot[base + 0];
      sr1s[l * 16 + q]  = sinf(rot[base + 1] * 0.5f);
      cr2s[l * 16 + q]  = cosf(rot[base + 2] * 0.5f);
    }
    if (t >= 96 && t < 184) {
      const int i = t - 96, l = i / 11, q = i % 11;
      cens[l * 16 + q] = 1.0f / (1.0f + expf(-ent[l * 11 + q]));
    }
    if (t >= 184 && t < 196) tmbs[t - 184] = tanhf(meas[t - 184]);
    if (t >= 196 && t < 208) b1s[t - 196] = b1[t - 196];
    if (t >= 208 && t < 220) lgs[t - 208] = ln_g[t - 208];
    if (t >= 220 && t < 232) lbs[t - 220] = ln_b[t - 220];
    if (t < 144) { const int j = t / 12, q = t % 12; w1T[q * 16 + j] = w1[t]; }
  }
  __syncthreads();

  // out-GEMM weight fragments (hoisted; overlaps with circuit scheduling)
  float wa[12], wb[12];
#pragma unroll
  for (int q = 0; q < 12; ++q) {
    wa[q] = w2s[t * 12 + q];
    wb[q] = w2s[(t + 256) * 12 + q];
  }
  const float ba = b2s[t], bb = b2s[t + 256];

  const int lane = t & 63;
  const int wv   = t >> 6;
  const int grp  = lane >> 4;
  const int q    = lane & 15;        // active q < 12
  const int gb   = lane & 48;        // group base lane
  const bool act = (q < 12);
  const int cidx = (q == 11) ? 10 : q;

#pragma unroll
  for (int pass = 0; pass < 2; ++pass) {
    const int rl  = (pass << 4) + (wv << 2) + grp;   // 0..31
    const int row = (blockIdx.x << 5) + rl;

    float hq = act ? h_in[(size_t)row * 12 + q] : 0.0f;

    // layernorm over the 16-lane group (q>=12 contribute 0)
    float s = hq;
    s += __shfl_xor(s, 1); s += __shfl_xor(s, 2);
    s += __shfl_xor(s, 4); s += __shfl_xor(s, 8);
    const float mu = s * (1.0f / 12.0f);
    float d = act ? (hq - mu) : 0.0f;
    float v2 = d * d;
    v2 += __shfl_xor(v2, 1); v2 += __shfl_xor(v2, 2);
    v2 += __shfl_xor(v2, 4); v2 += __shfl_xor(v2, 8);
    const float inv = 1.0f / sqrtf(v2 * (1.0f / 12.0f) + 1e-5f);

    const float n   = d * inv * lgs[q] + lbs[q];
    const float enc = tanhf(n) * 3.14159265358979f;

    float st = 0.0f;
#pragma unroll
    for (int l = 0; l < 8; ++l) {
      const float rx = enc + rot0s[l * 16 + q];
      st = st * cosf(rx * 0.5f) + sr1s[l * 16 + q];
      st *= cr2s[l * 16 + q];
      if (l < 7) {
        const float stn = __shfl(st, lane + 1);
        const float stp = __shfl(st, lane - 1);
        const float c   = cens[l * 16 + cidx];
        const float other = (q == 11) ? stp : stn;
        st = st * (1.0f - c) + other * c;
      }
    }

    // noise (JAX partitionable threefry) + measurement tanh
    uint32_t x0 = 0u, x1 = (uint32_t)row * 12u + (uint32_t)q;
    threefry2x32(0u, 1234u, x0, x1);
    const uint32_t bits = x0 ^ x1;
    const float u01 = __uint_as_float((bits >> 9) | 0x3F800000u) - 1.0f;
    float u = u01 * 2.0f + (-0.99999994f);
    u = fmaxf(-0.99999994f, u);
    const float nrm = 1.41421356237f * erfinv_xla(u);
    const float m = tanhf(st * tmbs[q] + nrm * 0.01f);

    // mlp1: lane j(==q) computes hidden j for its row
    float acc1 = b1s[q];
#pragma unroll
    for (int qq = 0; qq < 12; ++qq) {
      const float mq = __shfl(m, gb + qq);
      acc1 = fmaf(mq, w1T[qq * 16 + q], acc1);
    }
    if (act) hid[rl * 12 + q] = fmaxf(acc1, 0.0f);
  }
  __syncthreads();

  // out-GEMM: 32 rows x 512 cols
  float* ob = out + (size_t)blockIdx.x * 32 * 512;
  for (int rr = 0; rr < 32; ++rr) {
    const float4 h0 = *(const float4*)&hid[rr * 12 + 0];
    const float4 h1 = *(const float4*)&hid[rr * 12 + 4];
    const float4 h2 = *(const float4*)&hid[rr * 12 + 8];
    const float hvv[12] = {h0.x, h0.y, h0.z, h0.w, h1.x, h1.y, h1.z, h1.w,
                           h2.x, h2.y, h2.z, h2.w};
    float a = ba, b = bb;
#pragma unroll
    for (int qq = 0; qq < 12; ++qq) {
      a = fmaf(hvv[qq], wa[qq], a);
      b = fmaf(hvv[qq], wb[qq], b);
    }
    ob[rr * 512 + t] = a;
    ob[rr * 512 + 256 + t] = b;
  }
}

extern "C" void kernel_launch(void* const* d_in, const int* in_sizes, int n_in,
                              void* d_out, int out_size, void* d_ws, size_t ws_size,
                              hipStream_t stream) {
  const float* x    = (const float*)d_in[0];
  const float* w_in = (const float*)d_in[1];
  const float* b_in = (const float*)d_in[2];
  const float* ln_g = (const float*)d_in[3];
  const float* ln_b = (const float*)d_in[4];
  const float* rot  = (const float*)d_in[5];
  const float* ent  = (const float*)d_in[6];
  const float* w1   = (const float*)d_in[7];
  const float* b1   = (const float*)d_in[8];
  const float* w2   = (const float*)d_in[9];
  const float* b2   = (const float*)d_in[10];
  const float* mb   = (const float*)d_in[11];
  float* outp = (float*)d_out;
  float* h    = (float*)d_ws;  // 32768*12 floats = 1.57 MB scratch

  qnn_gemm_in<<<1024, 256, 0, stream>>>(x, w_in, b_in, h);
  qnn_tail<<<1024, 256, 0, stream>>>(h, ln_g, ln_b, rot, ent, w1, b1, w2, b2, mb, outp);
}

// Round 11
// 279.748 us; speedup vs baseline: 1.4094x; 1.4094x over previous
//
#include <hip/hip_runtime.h>
#include <cstdint>
#include <cstddef>

// ---------------------------------------------------------------------------
// QuantumNeuralNetwork fused pipeline for MI355X (gfx950)  — R10 (resubmit)
//   K1 REWRITTEN (R8/R9 spilled: acc[4][12]+xv reg tiles vs 84-128 VGPR caps
//   -> 50-240MB scratch traffic). New structure is low-VGPR by construction:
//     grid 512 x 256thr; block = 64 rows, lane <-> row; wave w owns K-quarter.
//     x: [64][64] f32 tiles double-buffered in LDS (stride 80 dw = 2-way),
//        staged global->reg->LDS, issue-early/write-late.
//     w: global loads, wave-uniform address -> L1 broadcast (L2-resident 48KB).
//     12 acc/lane, NO per-row cross-lane reduction; cross-wave partials via
//     small padded LDS buffer. Live set ~50 VGPR.
//   K2 unchanged (R2 lane-per-(row,qubit) design, passing).
// Noise = JAX partitionable threefry: bits(i) = o0^o1 of
// threefry2x32(key=(0,1234), count=(0,i)), then XLA uniform->erfinv normal.
// ---------------------------------------------------------------------------

__device__ __forceinline__ uint32_t rotl32(uint32_t x, int r) {
  return (x << r) | (x >> (32 - r));
}

__device__ __forceinline__ void threefry2x32(uint32_t k0, uint32_t k1,
                                             uint32_t& x0, uint32_t& x1) {
  const uint32_t k2 = k0 ^ k1 ^ 0x1BD11BDAu;
  x0 += k0; x1 += k1;
#define TF_R(r) { x0 += x1; x1 = rotl32(x1, (r)); x1 ^= x0; }
  TF_R(13) TF_R(15) TF_R(26) TF_R(6)
  x0 += k1; x1 += k2 + 1u;
  TF_R(17) TF_R(29) TF_R(16) TF_R(24)
  x0 += k2; x1 += k0 + 2u;
  TF_R(13) TF_R(15) TF_R(26) TF_R(6)
  x0 += k0; x1 += k1 + 3u;
  TF_R(17) TF_R(29) TF_R(16) TF_R(24)
  x0 += k1; x1 += k2 + 4u;
  TF_R(13) TF_R(15) TF_R(26) TF_R(6)
  x0 += k2; x1 += k0 + 5u;
#undef TF_R
}

__device__ __forceinline__ float erfinv_xla(float x) {
  float w = -log1pf(-x * x);
  float p;
  if (w < 5.0f) {
    w -= 2.5f;
    p = 2.81022636e-08f;
    p = fmaf(p, w, 3.43273939e-07f);
    p = fmaf(p, w, -3.5233877e-06f);
    p = fmaf(p, w, -4.39150654e-06f);
    p = fmaf(p, w, 0.00021858087f);
    p = fmaf(p, w, -0.00125372503f);
    p = fmaf(p, w, -0.00417768164f);
    p = fmaf(p, w, 0.246640727f);
    p = fmaf(p, w, 1.50140941f);
  } else {
    w = sqrtf(w) - 3.0f;
    p = -0.000200214257f;
    p = fmaf(p, w, 0.000100950558f);
    p = fmaf(p, w, 0.00134934322f);
    p = fmaf(p, w, -0.00367342844f);
    p = fmaf(p, w, 0.00573950773f);
    p = fmaf(p, w, -0.0076224613f);
    p = fmaf(p, w, 0.00943887047f);
    p = fmaf(p, w, 1.00167406f);
    p = fmaf(p, w, 2.83297682f);
  }
  return p * x;
}

// ---------------------------------------------------------------------------
// K1: h[32768][12] = x @ w_in.T + b_in.   grid 512 x block 256.
// ---------------------------------------------------------------------------
__global__ __launch_bounds__(256, 2)
void qnn_gemm_in(const float* __restrict__ x, const float* __restrict__ w_in,
                 const float* __restrict__ b_in, float* __restrict__ h) {
  __shared__ float xs[2][64][80];     // x tile [row][64k], stride 80 dw (2-way)
  __shared__ float ps[4][64][16];     // partials [wave][row][12+pad]

  const int tid  = threadIdx.x;
  const int wave = tid >> 6;
  const int lane = tid & 63;
  const int rowg = blockIdx.x << 6;

  const int brow = tid >> 4;          // 0..15 stage base row
  const int col4 = tid & 15;          // stage float4 column

  float acc[12];
#pragma unroll
  for (int q = 0; q < 12; ++q) acc[q] = 0.0f;

  float4 st0, st1, st2, st3;

#define K1_STAGE_LOAD(T)                                                       \
  {                                                                            \
    const float* gb = x + (size_t)(rowg + brow) * 1024 + ((T) << 6) + (col4 << 2); \
    st0 = *(const float4*)(gb);                                                \
    st1 = *(const float4*)(gb + 16 * 1024);                                    \
    st2 = *(const float4*)(gb + 32 * 1024);                                    \
    st3 = *(const float4*)(gb + 48 * 1024);                                    \
  }

#define K1_STAGE_WRITE(BUF)                                                    \
  {                                                                            \
    *(float4*)&xs[BUF][brow +  0][col4 << 2] = st0;                            \
    *(float4*)&xs[BUF][brow + 16][col4 << 2] = st1;                            \
    *(float4*)&xs[BUF][brow + 32][col4 << 2] = st2;                            \
    *(float4*)&xs[BUF][brow + 48][col4 << 2] = st3;                            \
  }

  // prologue: tile 0
  K1_STAGE_LOAD(0)
  K1_STAGE_WRITE(0)
  __syncthreads();

  for (int t = 0; t < 16; ++t) {
    const int cur = t & 1;
    if (t < 15) K1_STAGE_LOAD(t + 1)       // issue early (hides under compute)

    const int kb = (t << 6) + (wave << 4);  // global k base for this wave
#pragma unroll
    for (int kc = 0; kc < 4; ++kc) {
      const float4 xv = *(const float4*)&xs[cur][lane][(wave << 4) + (kc << 2)];
      const int kofs = kb + (kc << 2);
#pragma unroll
      for (int q = 0; q < 12; ++q) {
        const float4 wv = *(const float4*)&w_in[q * 1024 + kofs];  // uniform -> L1 bcast
        acc[q] = fmaf(xv.x, wv.x,
                 fmaf(xv.y, wv.y,
                 fmaf(xv.z, wv.z,
                 fmaf(xv.w, wv.w, acc[q]))));
      }
    }

    __syncthreads();                        // all reads of other buffer done
    if (t < 15) {
      K1_STAGE_WRITE(cur ^ 1)               // write late (vmcnt waited here)
      __syncthreads();
    }
  }
#undef K1_STAGE_LOAD
#undef K1_STAGE_WRITE

  // cross-wave reduction via LDS partials
  *(float4*)&ps[wave][lane][0] = make_float4(acc[0], acc[1], acc[2], acc[3]);
  *(float4*)&ps[wave][lane][4] = make_float4(acc[4], acc[5], acc[6], acc[7]);
  *(float4*)&ps[wave][lane][8] = make_float4(acc[8], acc[9], acc[10], acc[11]);
  __syncthreads();

#pragma unroll
  for (int i = 0; i < 3; ++i) {
    const int o = tid + (i << 8);           // 0..767
    const int row = o / 12, q = o - row * 12;
    const float v = ps[0][row][q] + ps[1][row][q] + ps[2][row][q] + ps[3][row][q];
    h[(size_t)(rowg + row) * 12 + q] = v + b_in[q];
  }
}

// ---------------------------------------------------------------------------
// K2: grid 1024 x block 256, 32 rows/block (4 blocks/CU).
// Circuit: lane-per-(row,qubit): 16-lane groups, q = lane&15 (q<12 active),
// 4 rows/wave/pass, 2 passes. Entangle via __shfl(lane+/-1), LN via shfl_xor,
// mlp1 via 12 shfl broadcasts. Out-GEMM: thread t -> cols t, t+256.
// ---------------------------------------------------------------------------
__global__ __launch_bounds__(256, 4)
void qnn_tail(const float* __restrict__ h_in,
              const float* __restrict__ ln_g, const float* __restrict__ ln_b,
              const float* __restrict__ rot,  const float* __restrict__ ent,
              const float* __restrict__ w1,   const float* __restrict__ b1,
              const float* __restrict__ w2,   const float* __restrict__ b2,
              const float* __restrict__ meas, float* __restrict__ out) {
  __shared__ float w2s[512 * 12];
  __shared__ float b2s[512];
  __shared__ float hid[32 * 12];
  __shared__ float rot0s[8 * 16], sr1s[8 * 16], cr2s[8 * 16], cens[8 * 16];
  __shared__ float tmbs[16], w1T[12 * 16], b1s[16], lgs[16], lbs[16];

  const int t = threadIdx.x;

  {  // staging
    const float4* s = (const float4*)w2;
    float4* d = (float4*)w2s;
#pragma unroll
    for (int j = 0; j < 6; ++j) d[t + 256 * j] = s[t + 256 * j];
    if (t < 128) ((float4*)b2s)[t] = ((const float4*)b2)[t];
    if (t < 96) {
      const int l = t / 12, q = t % 12, base = (l * 12 + q) * 3;
      rot0s[l * 16 + q] = rot[base + 0];
      sr1s[l * 16 + q]  = sinf(rot[base + 1] * 0.5f);
      cr2s[l * 16 + q]  = cosf(rot[base + 2] * 0.5f);
    }
    if (t >= 96 && t < 184) {
      const int i = t - 96, l = i / 11, q = i % 11;
      cens[l * 16 + q] = 1.0f / (1.0f + expf(-ent[l * 11 + q]));
    }
    if (t >= 184 && t < 196) tmbs[t - 184] = tanhf(meas[t - 184]);
    if (t >= 196 && t < 208) b1s[t - 196] = b1[t - 196];
    if (t >= 208 && t < 220) lgs[t - 208] = ln_g[t - 208];
    if (t >= 220 && t < 232) lbs[t - 220] = ln_b[t - 220];
    if (t < 144) { const int j = t / 12, q = t % 12; w1T[q * 16 + j] = w1[t]; }
  }
  __syncthreads();

  // out-GEMM weight fragments (hoisted; overlaps with circuit scheduling)
  float wa[12], wb[12];
#pragma unroll
  for (int q = 0; q < 12; ++q) {
    wa[q] = w2s[t * 12 + q];
    wb[q] = w2s[(t + 256) * 12 + q];
  }
  const float ba = b2s[t], bb = b2s[t + 256];

  const int lane = t & 63;
  const int wv   = t >> 6;
  const int grp  = lane >> 4;
  const int q    = lane & 15;        // active q < 12
  const int gb   = lane & 48;        // group base lane
  const bool act = (q < 12);
  const int cidx = (q == 11) ? 10 : q;

#pragma unroll
  for (int pass = 0; pass < 2; ++pass) {
    const int rl  = (pass << 4) + (wv << 2) + grp;   // 0..31
    const int row = (blockIdx.x << 5) + rl;

    float hq = act ? h_in[(size_t)row * 12 + q] : 0.0f;

    // layernorm over the 16-lane group (q>=12 contribute 0)
    float s = hq;
    s += __shfl_xor(s, 1); s += __shfl_xor(s, 2);
    s += __shfl_xor(s, 4); s += __shfl_xor(s, 8);
    const float mu = s * (1.0f / 12.0f);
    float d = act ? (hq - mu) : 0.0f;
    float v2 = d * d;
    v2 += __shfl_xor(v2, 1); v2 += __shfl_xor(v2, 2);
    v2 += __shfl_xor(v2, 4); v2 += __shfl_xor(v2, 8);
    const float inv = 1.0f / sqrtf(v2 * (1.0f / 12.0f) + 1e-5f);

    const float n   = d * inv * lgs[q] + lbs[q];
    const float enc = tanhf(n) * 3.14159265358979f;

    float st = 0.0f;
#pragma unroll
    for (int l = 0; l < 8; ++l) {
      const float rx = enc + rot0s[l * 16 + q];
      st = st * cosf(rx * 0.5f) + sr1s[l * 16 + q];
      st *= cr2s[l * 16 + q];
      if (l < 7) {
        const float stn = __shfl(st, lane + 1);
        const float stp = __shfl(st, lane - 1);
        const float c   = cens[l * 16 + cidx];
        const float other = (q == 11) ? stp : stn;
        st = st * (1.0f - c) + other * c;
      }
    }

    // noise (JAX partitionable threefry) + measurement tanh
    uint32_t x0 = 0u, x1 = (uint32_t)row * 12u + (uint32_t)q;
    threefry2x32(0u, 1234u, x0, x1);
    const uint32_t bits = x0 ^ x1;
    const float u01 = __uint_as_float((bits >> 9) | 0x3F800000u) - 1.0f;
    float u = u01 * 2.0f + (-0.99999994f);
    u = fmaxf(-0.99999994f, u);
    const float nrm = 1.41421356237f * erfinv_xla(u);
    const float m = tanhf(st * tmbs[q] + nrm * 0.01f);

    // mlp1: lane j(==q) computes hidden j for its row
    float acc1 = b1s[q];
#pragma unroll
    for (int qq = 0; qq < 12; ++qq) {
      const float mq = __shfl(m, gb + qq);
      acc1 = fmaf(mq, w1T[qq * 16 + q], acc1);
    }
    if (act) hid[rl * 12 + q] = fmaxf(acc1, 0.0f);
  }
  __syncthreads();

  // out-GEMM: 32 rows x 512 cols
  float* ob = out + (size_t)blockIdx.x * 32 * 512;
  for (int rr = 0; rr < 32; ++rr) {
    const float4 h0 = *(const float4*)&hid[rr * 12 + 0];
    const float4 h1 = *(const float4*)&hid[rr * 12 + 4];
    const float4 h2 = *(const float4*)&hid[rr * 12 + 8];
    const float hvv[12] = {h0.x, h0.y, h0.z, h0.w, h1.x, h1.y, h1.z, h1.w,
                           h2.x, h2.y, h2.z, h2.w};
    float a = ba, b = bb;
#pragma unroll
    for (int qq = 0; qq < 12; ++qq) {
      a = fmaf(hvv[qq], wa[qq], a);
      b = fmaf(hvv[qq], wb[qq], b);
    }
    ob[rr * 512 + t] = a;
    ob[rr * 512 + 256 + t] = b;
  }
}

extern "C" void kernel_launch(void* const* d_in, const int* in_sizes, int n_in,
                              void* d_out, int out_size, void* d_ws, size_t ws_size,
                              hipStream_t stream) {
  const float* x    = (const float*)d_in[0];
  const float* w_in = (const float*)d_in[1];
  const float* b_in = (const float*)d_in[2];
  const float* ln_g = (const float*)d_in[3];
  const float* ln_b = (const float*)d_in[4];
  const float* rot  = (const float*)d_in[5];
  const float* ent  = (const float*)d_in[6];
  const float* w1   = (const float*)d_in[7];
  const float* b1   = (const float*)d_in[8];
  const float* w2   = (const float*)d_in[9];
  const float* b2   = (const float*)d_in[10];
  const float* mb   = (const float*)d_in[11];
  float* outp = (float*)d_out;
  float* h    = (float*)d_ws;  // 32768*12 floats = 1.57 MB scratch

  qnn_gemm_in<<<512, 256, 0, stream>>>(x, w_in, b_in, h);
  qnn_tail<<<1024, 256, 0, stream>>>(h, ln_g, ln_b, rot, ent, w1, b1, w2, b2, mb, outp);
}

// Round 12
// 265.103 us; speedup vs baseline: 1.4873x; 1.0552x over previous
//
#include <hip/hip_runtime.h>
#include <cstdint>
#include <cstddef>

// ---------------------------------------------------------------------------
// QuantumNeuralNetwork fused pipeline for MI355X (gfx950)  — R12
//   K1 = R9 structure (w in LDS, 12 ds_read/row; x global->reg ping-pong,
//   no in-loop barriers) with launch_bounds(256,2): R9's ONLY failure was
//   the (256,3) VGPR cap of 84 < ~105 live (R8 measured (256,2)->128).
//   R10/R11 (x staged via LDS + 2 barriers/tile) proved x-staging is pure
//   serialization: 3% load duty cycle, 92us, all pipes idle.
//   K2 unchanged (R2 lane-per-(row,qubit) design, passing).
// Noise = JAX partitionable threefry: bits(i) = o0^o1 of
// threefry2x32(key=(0,1234), count=(0,i)), then XLA uniform->erfinv normal.
// ---------------------------------------------------------------------------

__device__ __forceinline__ uint32_t rotl32(uint32_t x, int r) {
  return (x << r) | (x >> (32 - r));
}

__device__ __forceinline__ void threefry2x32(uint32_t k0, uint32_t k1,
                                             uint32_t& x0, uint32_t& x1) {
  const uint32_t k2 = k0 ^ k1 ^ 0x1BD11BDAu;
  x0 += k0; x1 += k1;
#define TF_R(r) { x0 += x1; x1 = rotl32(x1, (r)); x1 ^= x0; }
  TF_R(13) TF_R(15) TF_R(26) TF_R(6)
  x0 += k1; x1 += k2 + 1u;
  TF_R(17) TF_R(29) TF_R(16) TF_R(24)
  x0 += k2; x1 += k0 + 2u;
  TF_R(13) TF_R(15) TF_R(26) TF_R(6)
  x0 += k0; x1 += k1 + 3u;
  TF_R(17) TF_R(29) TF_R(16) TF_R(24)
  x0 += k1; x1 += k2 + 4u;
  TF_R(13) TF_R(15) TF_R(26) TF_R(6)
  x0 += k2; x1 += k0 + 5u;
#undef TF_R
}

__device__ __forceinline__ float erfinv_xla(float x) {
  float w = -log1pf(-x * x);
  float p;
  if (w < 5.0f) {
    w -= 2.5f;
    p = 2.81022636e-08f;
    p = fmaf(p, w, 3.43273939e-07f);
    p = fmaf(p, w, -3.5233877e-06f);
    p = fmaf(p, w, -4.39150654e-06f);
    p = fmaf(p, w, 0.00021858087f);
    p = fmaf(p, w, -0.00125372503f);
    p = fmaf(p, w, -0.00417768164f);
    p = fmaf(p, w, 0.246640727f);
    p = fmaf(p, w, 1.50140941f);
  } else {
    w = sqrtf(w) - 3.0f;
    p = -0.000200214257f;
    p = fmaf(p, w, 0.000100950558f);
    p = fmaf(p, w, 0.00134934322f);
    p = fmaf(p, w, -0.00367342844f);
    p = fmaf(p, w, 0.00573950773f);
    p = fmaf(p, w, -0.0076224613f);
    p = fmaf(p, w, 0.00943887047f);
    p = fmaf(p, w, 1.00167406f);
    p = fmaf(p, w, 2.83297682f);
  }
  return p * x;
}

// ---------------------------------------------------------------------------
// K1: h[32768][12] = x @ w_in.T + b_in.
// grid 1024 x block 256 (4 waves). Wave covers 8 rows (2 R-blocks of 4).
// Lane l owns k = ks*256 + l*4 .. +3 for ks=0..3. Per R-block:
//   ks-outer, ping-pong xA/xB (2x4 float4 = 32 regs), acc[4][12] (48 regs).
//   48 unique ds_read_b128 of w (conflict-free: 256 consecutive dwords),
//   768 FMA, 6-stage shfl_xor butterfly, lanes 0..11 write 48B row.
// launch_bounds(256,2): VGPR cap 128 (measured R8); live set ~105. The
// (256,3) variant caps at 84 -> catastrophic spill (R9: 240MB scratch).
// ---------------------------------------------------------------------------
__global__ __launch_bounds__(256, 2)
void qnn_gemm_in(const float* __restrict__ x, const float* __restrict__ w_in,
                 const float* __restrict__ b_in, float* __restrict__ h) {
  __shared__ float wl[12 * 1024];
  {
    const float4* ws = (const float4*)w_in;
    float4* wd = (float4*)wl;
#pragma unroll
    for (int j = 0; j < 12; ++j) wd[threadIdx.x + 256 * j] = ws[threadIdx.x + 256 * j];
  }
  __syncthreads();

  const int wave = threadIdx.x >> 6;
  const int lane = threadIdx.x & 63;
  const float bmy = (lane < 12) ? b_in[lane] : 0.0f;

#define K1_COMPUTE(KS, XV)                                                    \
  {                                                                           \
    _Pragma("unroll")                                                         \
    for (int q = 0; q < 12; ++q) {                                            \
      const float4 wv = *(const float4*)&wl[q * 1024 + ((KS) << 8) + (lane << 2)]; \
      _Pragma("unroll")                                                       \
      for (int r = 0; r < 4; ++r) {                                           \
        acc[r][q] = fmaf(XV[r].x, wv.x,                                       \
                    fmaf(XV[r].y, wv.y,                                       \
                    fmaf(XV[r].z, wv.z,                                       \
                    fmaf(XV[r].w, wv.w, acc[r][q]))));                        \
      }                                                                       \
    }                                                                         \
  }

#pragma unroll
  for (int blk = 0; blk < 2; ++blk) {
    const int row0 = (blockIdx.x << 5) + (wave << 3) + (blk << 2);
    const float* xb = x + (size_t)row0 * 1024;

    float acc[4][12];
#pragma unroll
    for (int r = 0; r < 4; ++r)
#pragma unroll
      for (int q = 0; q < 12; ++q) acc[r][q] = 0.0f;

    float4 xA[4], xB[4];
#pragma unroll
    for (int r = 0; r < 4; ++r) xA[r] = ((const float4*)(xb + r * 1024))[lane];        // ks0
#pragma unroll
    for (int r = 0; r < 4; ++r) xB[r] = ((const float4*)(xb + r * 1024))[64 + lane];   // ks1

    K1_COMPUTE(0, xA)
#pragma unroll
    for (int r = 0; r < 4; ++r) xA[r] = ((const float4*)(xb + r * 1024))[128 + lane];  // ks2
    K1_COMPUTE(1, xB)
#pragma unroll
    for (int r = 0; r < 4; ++r) xB[r] = ((const float4*)(xb + r * 1024))[192 + lane];  // ks3
    K1_COMPUTE(2, xA)
    K1_COMPUTE(3, xB)

#pragma unroll
    for (int r = 0; r < 4; ++r) {
      float hv[12];
#pragma unroll
      for (int q = 0; q < 12; ++q) {
        float v = acc[r][q];
        v += __shfl_xor(v, 1);
        v += __shfl_xor(v, 2);
        v += __shfl_xor(v, 4);
        v += __shfl_xor(v, 8);
        v += __shfl_xor(v, 16);
        v += __shfl_xor(v, 32);
        hv[q] = v;
      }
      float outv = hv[0];
#pragma unroll
      for (int q = 1; q < 12; ++q) outv = (lane == q) ? hv[q] : outv;
      if (lane < 12) h[(size_t)(row0 + r) * 12 + lane] = outv + bmy;
    }
  }
#undef K1_COMPUTE
}

// ---------------------------------------------------------------------------
// K2: grid 1024 x block 256, 32 rows/block (4 blocks/CU).
// Circuit: lane-per-(row,qubit): 16-lane groups, q = lane&15 (q<12 active),
// 4 rows/wave/pass, 2 passes. Entangle via __shfl(lane+/-1), LN via shfl_xor,
// mlp1 via 12 shfl broadcasts. Out-GEMM: thread t -> cols t, t+256.
// ---------------------------------------------------------------------------
__global__ __launch_bounds__(256, 4)
void qnn_tail(const float* __restrict__ h_in,
              const float* __restrict__ ln_g, const float* __restrict__ ln_b,
              const float* __restrict__ rot,  const float* __restrict__ ent,
              const float* __restrict__ w1,   const float* __restrict__ b1,
              const float* __restrict__ w2,   const float* __restrict__ b2,
              const float* __restrict__ meas, float* __restrict__ out) {
  __shared__ float w2s[512 * 12];
  __shared__ float b2s[512];
  __shared__ float hid[32 * 12];
  __shared__ float rot0s[8 * 16], sr1s[8 * 16], cr2s[8 * 16], cens[8 * 16];
  __shared__ float tmbs[16], w1T[12 * 16], b1s[16], lgs[16], lbs[16];

  const int t = threadIdx.x;

  {  // staging
    const float4* s = (const float4*)w2;
    float4* d = (float4*)w2s;
#pragma unroll
    for (int j = 0; j < 6; ++j) d[t + 256 * j] = s[t + 256 * j];
    if (t < 128) ((float4*)b2s)[t] = ((const float4*)b2)[t];
    if (t < 96) {
      const int l = t / 12, q = t % 12, base = (l * 12 + q) * 3;
      rot0s[l * 16 + q] = rot[base + 0];
      sr1s[l * 16 + q]  = sinf(rot[base + 1] * 0.5f);
      cr2s[l * 16 + q]  = cosf(rot[base + 2] * 0.5f);
    }
    if (t >= 96 && t < 184) {
      const int i = t - 96, l = i / 11, q = i % 11;
      cens[l * 16 + q] = 1.0f / (1.0f + expf(-ent[l * 11 + q]));
    }
    if (t >= 184 && t < 196) tmbs[t - 184] = tanhf(meas[t - 184]);
    if (t >= 196 && t < 208) b1s[t - 196] = b1[t - 196];
    if (t >= 208 && t < 220) lgs[t - 208] = ln_g[t - 208];
    if (t >= 220 && t < 232) lbs[t - 220] = ln_b[t - 220];
    if (t < 144) { const int j = t / 12, q = t % 12; w1T[q * 16 + j] = w1[t]; }
  }
  __syncthreads();

  // out-GEMM weight fragments (hoisted; overlaps with circuit scheduling)
  float wa[12], wb[12];
#pragma unroll
  for (int q = 0; q < 12; ++q) {
    wa[q] = w2s[t * 12 + q];
    wb[q] = w2s[(t + 256) * 12 + q];
  }
  const float ba = b2s[t], bb = b2s[t + 256];

  const int lane = t & 63;
  const int wv   = t >> 6;
  const int grp  = lane >> 4;
  const int q    = lane & 15;        // active q < 12
  const int gb   = lane & 48;        // group base lane
  const bool act = (q < 12);
  const int cidx = (q == 11) ? 10 : q;

#pragma unroll
  for (int pass = 0; pass < 2; ++pass) {
    const int rl  = (pass << 4) + (wv << 2) + grp;   // 0..31
    const int row = (blockIdx.x << 5) + rl;

    float hq = act ? h_in[(size_t)row * 12 + q] : 0.0f;

    // layernorm over the 16-lane group (q>=12 contribute 0)
    float s = hq;
    s += __shfl_xor(s, 1); s += __shfl_xor(s, 2);
    s += __shfl_xor(s, 4); s += __shfl_xor(s, 8);
    const float mu = s * (1.0f / 12.0f);
    float d = act ? (hq - mu) : 0.0f;
    float v2 = d * d;
    v2 += __shfl_xor(v2, 1); v2 += __shfl_xor(v2, 2);
    v2 += __shfl_xor(v2, 4); v2 += __shfl_xor(v2, 8);
    const float inv = 1.0f / sqrtf(v2 * (1.0f / 12.0f) + 1e-5f);

    const float n   = d * inv * lgs[q] + lbs[q];
    const float enc = tanhf(n) * 3.14159265358979f;

    float st = 0.0f;
#pragma unroll
    for (int l = 0; l < 8; ++l) {
      const float rx = enc + rot0s[l * 16 + q];
      st = st * cosf(rx * 0.5f) + sr1s[l * 16 + q];
      st *= cr2s[l * 16 + q];
      if (l < 7) {
        const float stn = __shfl(st, lane + 1);
        const float stp = __shfl(st, lane - 1);
        const float c   = cens[l * 16 + cidx];
        const float other = (q == 11) ? stp : stn;
        st = st * (1.0f - c) + other * c;
      }
    }

    // noise (JAX partitionable threefry) + measurement tanh
    uint32_t x0 = 0u, x1 = (uint32_t)row * 12u + (uint32_t)q;
    threefry2x32(0u, 1234u, x0, x1);
    const uint32_t bits = x0 ^ x1;
    const float u01 = __uint_as_float((bits >> 9) | 0x3F800000u) - 1.0f;
    float u = u01 * 2.0f + (-0.99999994f);
    u = fmaxf(-0.99999994f, u);
    const float nrm = 1.41421356237f * erfinv_xla(u);
    const float m = tanhf(st * tmbs[q] + nrm * 0.01f);

    // mlp1: lane j(==q) computes hidden j for its row
    float acc1 = b1s[q];
#pragma unroll
    for (int qq = 0; qq < 12; ++qq) {
      const float mq = __shfl(m, gb + qq);
      acc1 = fmaf(mq, w1T[qq * 16 + q], acc1);
    }
    if (act) hid[rl * 12 + q] = fmaxf(acc1, 0.0f);
  }
  __syncthreads();

  // out-GEMM: 32 rows x 512 cols
  float* ob = out + (size_t)blockIdx.x * 32 * 512;
  for (int rr = 0; rr < 32; ++rr) {
    const float4 h0 = *(const float4*)&hid[rr * 12 + 0];
    const float4 h1 = *(const float4*)&hid[rr * 12 + 4];
    const float4 h2 = *(const float4*)&hid[rr * 12 + 8];
    const float hvv[12] = {h0.x, h0.y, h0.z, h0.w, h1.x, h1.y, h1.z, h1.w,
                           h2.x, h2.y, h2.z, h2.w};
    float a = ba, b = bb;
#pragma unroll
    for (int qq = 0; qq < 12; ++qq) {
      a = fmaf(hvv[qq], wa[qq], a);
      b = fmaf(hvv[qq], wb[qq], b);
    }
    ob[rr * 512 + t] = a;
    ob[rr * 512 + 256 + t] = b;
  }
}

extern "C" void kernel_launch(void* const* d_in, const int* in_sizes, int n_in,
                              void* d_out, int out_size, void* d_ws, size_t ws_size,
                              hipStream_t stream) {
  const float* x    = (const float*)d_in[0];
  const float* w_in = (const float*)d_in[1];
  const float* b_in = (const float*)d_in[2];
  const float* ln_g = (const float*)d_in[3];
  const float* ln_b = (const float*)d_in[4];
  const float* rot  = (const float*)d_in[5];
  const float* ent  = (const float*)d_in[6];
  const float* w1   = (const float*)d_in[7];
  const float* b1   = (const float*)d_in[8];
  const float* w2   = (const float*)d_in[9];
  const float* b2   = (const float*)d_in[10];
  const float* mb   = (const float*)d_in[11];
  float* outp = (float*)d_out;
  float* h    = (float*)d_ws;  // 32768*12 floats = 1.57 MB scratch

  qnn_gemm_in<<<1024, 256, 0, stream>>>(x, w_in, b_in, h);
  qnn_tail<<<1024, 256, 0, stream>>>(h, ln_g, ln_b, rot, ent, w1, b1, w2, b2, mb, outp);
}